// Round 17
// baseline (2522.454 us; speedup 1.0000x reference)
//
#include <hip/hip_runtime.h>
#include <math.h>

#define E 256
#define NTOK 1024
#define NB 32
#define NLAYER 12
#define LN_EPS 1e-5f

typedef __attribute__((ext_vector_type(8))) short bf16x8;
typedef __attribute__((ext_vector_type(4))) float f32x4;
#define MFMA16(a, b, c) __builtin_amdgcn_mfma_f32_16x16x32_bf16(a, b, c, 0, 0, 0)

__device__ __forceinline__ ushort f2bf(float f) {
    union { float f; unsigned u; } v; v.f = f;
    return (ushort)((v.u + 0x7fffu + ((v.u >> 16) & 1u)) >> 16);
}
__device__ __forceinline__ float bf2f(ushort u) {
    union { unsigned u; float f; } v; v.u = (unsigned)u << 16;
    return v.f;
}

// ---------------------------------------------------------------- weight prep
__global__ __launch_bounds__(256) void k_wprep(
    const float* __restrict__ Wq, const float* __restrict__ Wk, const float* __restrict__ Wv,
    const float* __restrict__ W1, const float* __restrict__ W2,
    ushort* __restrict__ WT)
{
    const int mat = blockIdx.x % 5;
    const int l   = blockIdx.x / 5;
    const float* src = (mat == 0 ? Wq : mat == 1 ? Wk : mat == 2 ? Wv : mat == 3 ? W1 : W2)
                       + (size_t)l * E * E;
    ushort* dst = WT + ((size_t)(l * 5 + mat) << 16);
    const int n = threadIdx.x;
    #pragma unroll
    for (int c = 0; c < 4; ++c) {
        #pragma unroll
        for (int j = 0; j < 8; ++j) {
            const int k0 = c * 64 + j * 8;
            uint4 u;
            u.x = (uint)f2bf(src[(size_t)(k0 + 0) * E + n]) | ((uint)f2bf(src[(size_t)(k0 + 1) * E + n]) << 16);
            u.y = (uint)f2bf(src[(size_t)(k0 + 2) * E + n]) | ((uint)f2bf(src[(size_t)(k0 + 3) * E + n]) << 16);
            u.z = (uint)f2bf(src[(size_t)(k0 + 4) * E + n]) | ((uint)f2bf(src[(size_t)(k0 + 5) * E + n]) << 16);
            u.w = (uint)f2bf(src[(size_t)(k0 + 6) * E + n]) | ((uint)f2bf(src[(size_t)(k0 + 7) * E + n]) << 16);
            *(uint4*)&dst[(size_t)n * E + k0] = u;
        }
    }
}

// ---------------------------------------------------------------- embed (bf16 residual; XCD-affine)
__global__ __launch_bounds__(256) void k_embed(
    const float* __restrict__ xs, const float* __restrict__ ys,
    const float* __restrict__ W_in, const float* __restrict__ b_in,
    ushort* __restrict__ Hb)
{
    __shared__ float zs[16][64];
    const int tid = threadIdx.x;
    const int bid = blockIdx.x;
    const int r0 = (bid & 31) * NTOK + (bid >> 5) * 16;   // batch = bid&31 -> XCD b%8
    #pragma unroll
    for (int l = 0; l < 4; ++l) {
        int lin = tid + l * 256;
        int i = lin >> 6, d = lin & 63;
        int row = r0 + i;
        int t = row & (NTOK - 1);
        float v;
        if (d < 63) v = xs[(size_t)row * 63 + d];
        else        v = (t == NTOK - 1) ? 0.f : ys[row];
        zs[i][d] = v;
    }
    __syncthreads();
    float acc[16];
    #pragma unroll
    for (int i = 0; i < 16; ++i) acc[i] = 0.f;
    for (int d = 0; d < 64; ++d) {
        float w = W_in[d * E + tid];
        #pragma unroll
        for (int i = 0; i < 16; ++i) acc[i] = fmaf(zs[i][d], w, acc[i]);
    }
    float bb = b_in[tid];
    #pragma unroll
    for (int i = 0; i < 16; ++i)
        Hb[(size_t)(r0 + i) * E + tid] = f2bf(acc[i] + bb);
}

// ---------------------------------------------------------------- qkv helpers (ALL static indexing)
// GEMM with register-prefetched weight staging (race-free: registers private).
__device__ __forceinline__ void qkv_gemm(
    const ushort* __restrict__ Wt, const ushort* __restrict__ Hb,
    size_t r0, int tid, int w, int lr, int lg,
    ushort (&Ws)[256][72], f32x4 (&acc)[4][4])
{
    #pragma unroll
    for (int mt = 0; mt < 4; ++mt)
        #pragma unroll
        for (int nt = 0; nt < 4; ++nt) acc[mt][nt] = (f32x4){0.f, 0.f, 0.f, 0.f};

    const int sn = tid >> 3;
    const int ss = tid & 7;
    bf16x8 c[8];
    #pragma unroll
    for (int rep = 0; rep < 8; ++rep)
        c[rep] = *(const bf16x8*)&Wt[(size_t)(rep * 32 + sn) * E + ss * 8];

    #pragma unroll 1
    for (int kc = 0; kc < 4; ++kc) {
        __syncthreads();                          // prev compute done reading Ws
        #pragma unroll
        for (int rep = 0; rep < 8; ++rep)
            *(bf16x8*)&Ws[rep * 32 + sn][ss * 8] = c[rep];
        {                                         // prefetch next chunk (wraps; unused at kc=3)
            const int kn = ((kc + 1) & 3) * 64;
            #pragma unroll
            for (int rep = 0; rep < 8; ++rep)
                c[rep] = *(const bf16x8*)&Wt[(size_t)(rep * 32 + sn) * E + kn + ss * 8];
        }
        __syncthreads();
        #pragma unroll
        for (int kl = 0; kl < 2; ++kl) {
            bf16x8 af[4], bw[4];
            #pragma unroll
            for (int mt = 0; mt < 4; ++mt)
                af[mt] = *(const bf16x8*)&Hb[(r0 + mt * 16 + lr) * E + kc * 64 + kl * 32 + lg * 8];
            #pragma unroll
            for (int nt = 0; nt < 4; ++nt)
                bw[nt] = *(const bf16x8*)&Ws[w * 64 + nt * 16 + lr][kl * 32 + lg * 8];
            #pragma unroll
            for (int mt = 0; mt < 4; ++mt)
                #pragma unroll
                for (int nt = 0; nt < 4; ++nt)
                    acc[mt][nt] = MFMA16(af[mt], bw[nt], acc[mt][nt]);
        }
    }
}

__device__ __forceinline__ void qkv_out_qk(
    ushort* __restrict__ Out, size_t r0, int w, int l, int lr, int lg,
    ushort (&ScW)[16][72], f32x4 (&acc)[4][4])
{
    #pragma unroll
    for (int mt = 0; mt < 4; ++mt) {              // STATIC mt: acc stays in registers
        #pragma unroll
        for (int nt = 0; nt < 4; ++nt)
            #pragma unroll
            for (int r = 0; r < 4; ++r)
                ScW[lg * 4 + r][nt * 16 + lr] = f2bf(acc[mt][nt][r]);
        #pragma unroll
        for (int j = 0; j < 2; ++j) {             // same-wave RAW via LDS
            bf16x8 v = *(const bf16x8*)&ScW[l >> 2][(l & 3) * 16 + j * 8];
            *(bf16x8*)&Out[(r0 + mt * 16 + (l >> 2)) * E + w * 64 + (l & 3) * 16 + j * 8] = v;
        }
    }
}

// ---------------------------------------------------------------- MFMA qkv (register-blocked; XCD-affine)
__global__ __launch_bounds__(256, 2) void k_qkv(
    const ushort* __restrict__ Hb,
    const ushort* __restrict__ WqT, const ushort* __restrict__ WkT, const ushort* __restrict__ WvT,
    ushort* __restrict__ Qb, ushort* __restrict__ Kb, ushort* __restrict__ VTg)
{
    __shared__ __align__(16) ushort Ws[256][72];    // weights chunk; reused as V out-stage
    __shared__ __align__(16) ushort Sc[4][16][72];  // per-wave Q/K out-scratch
    const int tid = threadIdx.x;
    const int w = tid >> 6, l = tid & 63;
    const int lr = l & 15, lg = l >> 4;
    const int bid  = blockIdx.x;
    const int b    = bid & 31;                      // batch -> XCD b%8 (matches k_attn)
    const int tok0 = (bid >> 5) * 64;
    const size_t r0 = (size_t)b * NTOK + tok0;

    f32x4 acc[4][4];

    qkv_gemm(WqT, Hb, r0, tid, w, lr, lg, Ws, acc);
    qkv_out_qk(Qb, r0, w, l, lr, lg, Sc[w], acc);

    qkv_gemm(WkT, Hb, r0, tid, w, lr, lg, Ws, acc);
    qkv_out_qk(Kb, r0, w, l, lr, lg, Sc[w], acc);

    qkv_gemm(WvT, Hb, r0, tid, w, lr, lg, Ws, acc);
    // V epilogue: stage [e][tok] tile in Ws, then coalesced 128B copy-out
    __syncthreads();                              // all waves done reading weights
    #pragma unroll
    for (int mt = 0; mt < 4; ++mt)
        #pragma unroll
        for (int nt = 0; nt < 4; ++nt) {
            ushort4 u;
            u.x = f2bf(acc[mt][nt][0]); u.y = f2bf(acc[mt][nt][1]);
            u.z = f2bf(acc[mt][nt][2]); u.w = f2bf(acc[mt][nt][3]);
            *(ushort4*)&Ws[w * 64 + nt * 16 + lr][mt * 16 + lg * 4] = u;
        }
    __syncthreads();
    #pragma unroll
    for (int rep = 0; rep < 8; ++rep) {
        int lin = rep * 256 + tid;
        int row = lin >> 3, ch = lin & 7;         // 8 lanes = 128B contiguous per e-row
        bf16x8 v = *(const bf16x8*)&Ws[row][ch * 8];
        *(bf16x8*)&VTg[((size_t)b * E + row) * NTOK + tok0 + ch * 8] = v;
    }
}

// ---------------------------------------------------------------- MFMA attention + residual + LN1
// 512 thr = 8 waves x 16 q-rows, grid 256. K staged in LDS (reg-prefetched);
// V read DIRECTLY from global VTg (L2-pinned per XCD, L1-hot across the 8
// waves) — removes the VT LDS staging entirely (m169 precedent: V-staging at
// S=1024 is pure overhead when the tile L2-fits). Residual rows prefetched.
#define ATTN_LOAD_K(koff, ka, kb_)                                                       \
    ka  = *(const bf16x8*)&Kb [kvbase + (size_t)((koff) + (tid >> 5)) * E + (tid & 31) * 8];       \
    kb_ = *(const bf16x8*)&Kb [kvbase + (size_t)((koff) + 16 + (tid >> 5)) * E + (tid & 31) * 8];

__global__ __launch_bounds__(512, 2) void k_attn(
    const ushort* __restrict__ Qb, const ushort* __restrict__ Kb, const ushort* __restrict__ VTg,
    ushort* __restrict__ Hb,
    const float* __restrict__ g1, const float* __restrict__ be1)
{
    __shared__ __align__(16) ushort Ks[32][264];
    __shared__ __align__(16) ushort Pl[8][16][40];
    const int tid = threadIdx.x;
    const int w  = tid >> 6, l = tid & 63;
    const int lr = l & 15, lg = l >> 4;

    // bid mod 8 = batch mod 8 -> all 8 q-tiles of a batch on one XCD (4MB KV = L2)
    const int bid   = blockIdx.x;
    const int batch = bid & 31;
    const int tile  = bid >> 5;

    const size_t kvbase = (size_t)batch * NTOK * E;
    const size_t vtbase = (size_t)batch * E * NTOK;
    const int    qrow0  = tile * 128 + w * 16;
    const size_t qbase  = kvbase + (size_t)qrow0 * E;

    // Q fragments: 16 rows x 256, register-resident
    bf16x8 qf[8];
    #pragma unroll
    for (int kk = 0; kk < 8; ++kk)
        qf[kk] = *(const bf16x8*)&Qb[qbase + (size_t)lr * E + kk * 32 + lg * 8];

    // prefetch residual rows for the epilogue (latency hidden under K-loop)
    ushort hr[4][16];
    #pragma unroll
    for (int r = 0; r < 4; ++r)
        #pragma unroll
        for (int nt = 0; nt < 16; ++nt)
            hr[r][nt] = Hb[kvbase + (size_t)(qrow0 + lg * 4 + r) * E + nt * 16 + lr];

    f32x4 o[16];
    #pragma unroll
    for (int nt = 0; nt < 16; ++nt) o[nt] = (f32x4){0.f, 0.f, 0.f, 0.f};

    const float inv_n = 1.0f / (float)NTOK;
    // Pl column swizzle: XOR 8-chunk by bit3 of q-row
    const int wsw = ((lg >> 1) & 1) << 3;
    const int rsw = ((lr >> 3) & 1) << 3;

    // prologue: K tile 0 -> registers
    bf16x8 cka, ckb;
    ATTN_LOAD_K(0, cka, ckb);

    #pragma unroll 1
    for (int jt = 0; jt < 32; ++jt) {
        const int k0 = jt * 32;
        __syncthreads();                          // prior compute's Ks reads done (WAR)
        *(bf16x8*)&Ks[ 0 + (tid >> 5)][(tid & 31) * 8] = cka;
        *(bf16x8*)&Ks[16 + (tid >> 5)][(tid & 31) * 8] = ckb;
        // issue next K tile's global loads (registers only)
        bf16x8 nka, nkb;
        {
            const int kn = ((jt + 1) & 31) * 32;  // wraps at jt=31 (result unused)
            ATTN_LOAD_K(kn, nka, nkb);
        }
        __syncthreads();                          // staging visible to all waves

        // S = Q K^T (two 16-col tiles)
        f32x4 s0 = (f32x4){0.f, 0.f, 0.f, 0.f};
        f32x4 s1 = (f32x4){0.f, 0.f, 0.f, 0.f};
        #pragma unroll
        for (int kk = 0; kk < 8; ++kk) {
            bf16x8 b0 = *(const bf16x8*)&Ks[lr][kk * 32 + lg * 8];
            bf16x8 b1 = *(const bf16x8*)&Ks[16 + lr][kk * 32 + lg * 8];
            s0 = MFMA16(qf[kk], b0, s0);
            s1 = MFMA16(qf[kk], b1, s1);
        }
        // P = relu(S)/n -> Pl (col 8-chunk swizzled); same-wave write->read
        #pragma unroll
        for (int r = 0; r < 4; ++r) {
            Pl[w][lg * 4 + r][lr ^ wsw]        = f2bf(fmaxf(s0[r], 0.f) * inv_n);
            Pl[w][lg * 4 + r][(16 + lr) ^ wsw] = f2bf(fmaxf(s1[r], 0.f) * inv_n);
        }
        bf16x8 pa = *(const bf16x8*)&Pl[w][lr][(lg * 8) ^ rsw];
        // O += P V : B-frags direct from global (L1/L2-hot, shared by 8 waves)
        #pragma unroll
        for (int nt = 0; nt < 16; ++nt) {
            bf16x8 vb = *(const bf16x8*)&VTg[vtbase + (size_t)(nt * 16 + lr) * NTOK + k0 + lg * 8];
            o[nt] = MFMA16(pa, vb, o[nt]);
        }
        // rotate prefetch regs
        cka = nka; ckb = nkb;
    }

    // epilogue: residual (prefetched bf16 carrier) + LayerNorm (fp32 in-register)
    float gg[16], bb[16];
    #pragma unroll
    for (int nt = 0; nt < 16; ++nt) {
        gg[nt] = g1[nt * 16 + lr];
        bb[nt] = be1[nt * 16 + lr];
    }
    #pragma unroll
    for (int r = 0; r < 4; ++r) {
        const int q = lg * 4 + r;
        const size_t rowbase = kvbase + (size_t)(qrow0 + q) * E;
        float xv[16];
        float s = 0.f, s2 = 0.f;
        #pragma unroll
        for (int nt = 0; nt < 16; ++nt) {
            float val = bf2f(hr[r][nt]) + o[nt][r];
            xv[nt] = val;
            s += val; s2 += val * val;
        }
        #pragma unroll
        for (int m = 1; m < 16; m <<= 1) {
            s  += __shfl_xor(s, m, 64);
            s2 += __shfl_xor(s2, m, 64);
        }
        float mu = s * (1.f / 256.f);
        float rs = rsqrtf(s2 * (1.f / 256.f) - mu * mu + LN_EPS);
        #pragma unroll
        for (int nt = 0; nt < 16; ++nt) {
            float ov = (xv[nt] - mu) * rs * gg[nt] + bb[nt];
            Hb[rowbase + nt * 16 + lr] = f2bf(ov);
        }
    }
}

// ---------------------------------------------------------------- MFMA MLP (register-blocked; XCD-affine) + residual + LN2
__global__ __launch_bounds__(256, 2) void k_mlp(
    ushort* __restrict__ Hb,
    const ushort* __restrict__ W1T, const float* __restrict__ b1,
    const ushort* __restrict__ W2T, const float* __restrict__ b2,
    const float* __restrict__ g2, const float* __restrict__ be2)
{
    __shared__ __align__(16) ushort Ws[256][72];
    __shared__ __align__(16) ushort Ts[64][264];
    __shared__ float part[4][64][2];
    __shared__ float stats[64][2];
    const int tid = threadIdx.x;
    const int w = tid >> 6, l = tid & 63;
    const int lr = l & 15, lg = l >> 4;
    const int bid = blockIdx.x;
    const size_t r0 = (size_t)(bid & 31) * NTOK + (bid >> 5) * 64;  // XCD-affine
    const int sn = tid >> 3, ss = tid & 7;

    // ---- GEMM1: T = relu(H @ W1 + b1)   (reg-prefetched weight staging)
    f32x4 acc[4][4];
    qkv_gemm(W1T, Hb, r0, tid, w, lr, lg, Ws, acc);
    {
        float bb1[4];
        #pragma unroll
        for (int nt = 0; nt < 4; ++nt) bb1[nt] = b1[w * 64 + nt * 16 + lr];
        #pragma unroll
        for (int mt = 0; mt < 4; ++mt)
            #pragma unroll
            for (int nt = 0; nt < 4; ++nt)
                #pragma unroll
                for (int r = 0; r < 4; ++r)
                    Ts[mt * 16 + lg * 4 + r][w * 64 + nt * 16 + lr]
                        = f2bf(fmaxf(acc[mt][nt][r] + bb1[nt], 0.f));
    }

    // ---- GEMM2: out = T @ W2   (reg-prefetched weight staging)
    f32x4 acc2[4][4];
    #pragma unroll
    for (int mt = 0; mt < 4; ++mt)
        #pragma unroll
        for (int nt = 0; nt < 4; ++nt) acc2[mt][nt] = (f32x4){0.f, 0.f, 0.f, 0.f};
    bf16x8 c2[8];
    #pragma unroll
    for (int rep = 0; rep < 8; ++rep)
        c2[rep] = *(const bf16x8*)&W2T[(size_t)(rep * 32 + sn) * E + ss * 8];
    #pragma unroll 1
    for (int kc = 0; kc < 4; ++kc) {
        __syncthreads();                          // prev compute done; orders Ts writes->reads
        #pragma unroll
        for (int rep = 0; rep < 8; ++rep)
            *(bf16x8*)&Ws[rep * 32 + sn][ss * 8] = c2[rep];
        {
            const int kn = ((kc + 1) & 3) * 64;
            #pragma unroll
            for (int rep = 0; rep < 8; ++rep)
                c2[rep] = *(const bf16x8*)&W2T[(size_t)(rep * 32 + sn) * E + kn + ss * 8];
        }
        __syncthreads();
        #pragma unroll
        for (int kl = 0; kl < 2; ++kl) {
            bf16x8 af[4], bw[4];
            #pragma unroll
            for (int mt = 0; mt < 4; ++mt)
                af[mt] = *(const bf16x8*)&Ts[mt * 16 + lr][kc * 64 + kl * 32 + lg * 8];
            #pragma unroll
            for (int nt = 0; nt < 4; ++nt)
                bw[nt] = *(const bf16x8*)&Ws[w * 64 + nt * 16 + lr][kl * 32 + lg * 8];
            #pragma unroll
            for (int mt = 0; mt < 4; ++mt)
                #pragma unroll
                for (int nt = 0; nt < 4; ++nt)
                    acc2[mt][nt] = MFMA16(af[mt], bw[nt], acc2[mt][nt]);
        }
    }

    // ---- residual (bf16 carrier) + LN2 (cross-wave row reduction)
    {
        float b2v[4];
        #pragma unroll
        for (int nt = 0; nt < 4; ++nt) b2v[nt] = b2[w * 64 + nt * 16 + lr];
        #pragma unroll
        for (int mt = 0; mt < 4; ++mt)
            #pragma unroll
            for (int r = 0; r < 4; ++r)
                #pragma unroll
                for (int nt = 0; nt < 4; ++nt)
                    acc2[mt][nt][r] += bf2f(Hb[(r0 + mt * 16 + lg * 4 + r) * E + w * 64 + nt * 16 + lr])
                                       + b2v[nt];
    }
    #pragma unroll
    for (int mt = 0; mt < 4; ++mt)
        #pragma unroll
        for (int r = 0; r < 4; ++r) {
            float s = 0.f, s2 = 0.f;
            #pragma unroll
            for (int nt = 0; nt < 4; ++nt) {
                float v = acc2[mt][nt][r];
                s += v; s2 += v * v;
            }
            #pragma unroll
            for (int m = 1; m < 16; m <<= 1) {
                s  += __shfl_xor(s, m, 64);
                s2 += __shfl_xor(s2, m, 64);
            }
            if (lr == 0) {
                part[w][mt * 16 + lg * 4 + r][0] = s;
                part[w][mt * 16 + lg * 4 + r][1] = s2;
            }
        }
    __syncthreads();
    if (tid < 64) {
        float s = part[0][tid][0] + part[1][tid][0] + part[2][tid][0] + part[3][tid][0];
        float s2 = part[0][tid][1] + part[1][tid][1] + part[2][tid][1] + part[3][tid][1];
        float mu = s * (1.f / 256.f);
        stats[tid][0] = mu;
        stats[tid][1] = rsqrtf(s2 * (1.f / 256.f) - mu * mu + LN_EPS);
    }
    __syncthreads();
    {
        float gg[4], be[4];
        #pragma unroll
        for (int nt = 0; nt < 4; ++nt) {
            gg[nt] = g2[w * 64 + nt * 16 + lr];
            be[nt] = be2[w * 64 + nt * 16 + lr];
        }
        #pragma unroll
        for (int mt = 0; mt < 4; ++mt)
            #pragma unroll
            for (int r = 0; r < 4; ++r) {
                const int row = mt * 16 + lg * 4 + r;
                const float mu = stats[row][0], rs = stats[row][1];
                const size_t rowbase = (r0 + row) * E;
                #pragma unroll
                for (int nt = 0; nt < 4; ++nt) {
                    float ov = (acc2[mt][nt][r] - mu) * rs * gg[nt] + be[nt];
                    Hb[rowbase + w * 64 + nt * 16 + lr] = f2bf(ov);
                }
            }
    }
}

// ---------------------------------------------------------------- readout
__global__ __launch_bounds__(256) void k_readout(
    const ushort* __restrict__ Hb, const float* __restrict__ W_out,
    const float* __restrict__ b_out, float* __restrict__ out)
{
    const int tid = threadIdx.x;
    const int lane = tid & 63;
    const int row = blockIdx.x * 4 + (tid >> 6);
    float s = 0.f;
    #pragma unroll
    for (int j = 0; j < 4; ++j)
        s += bf2f(Hb[(size_t)row * E + j * 64 + lane]) * W_out[j * 64 + lane];
    #pragma unroll
    for (int m = 1; m < 64; m <<= 1) s += __shfl_xor(s, m, 64);
    if (lane == 0) out[row] = s + b_out[0];
}

// ----------------------------------------------------------------
extern "C" void kernel_launch(void* const* d_in, const int* in_sizes, int n_in,
                              void* d_out, int out_size, void* d_ws, size_t ws_size,
                              hipStream_t stream)
{
    const float* xs    = (const float*)d_in[0];
    const float* ys    = (const float*)d_in[1];
    const float* W_in  = (const float*)d_in[2];
    const float* b_in  = (const float*)d_in[3];
    const float* Wq    = (const float*)d_in[4];
    const float* Wk    = (const float*)d_in[5];
    const float* Wv    = (const float*)d_in[6];
    const float* g1    = (const float*)d_in[7];
    const float* be1   = (const float*)d_in[8];
    const float* W1    = (const float*)d_in[9];
    const float* b1    = (const float*)d_in[10];
    const float* W2    = (const float*)d_in[11];
    const float* b2    = (const float*)d_in[12];
    const float* g2    = (const float*)d_in[13];
    const float* be2   = (const float*)d_in[14];
    const float* W_out = (const float*)d_in[15];
    const float* b_out = (const float*)d_in[16];
    (void)in_sizes; (void)n_in; (void)out_size; (void)ws_size;

    const size_t SZ = (size_t)NB * NTOK * E;
    ushort* Hb  = (ushort*)d_ws;                    // bf16 residual stream
    ushort* Qb  = Hb + SZ;
    ushort* Kb  = Qb + SZ;
    ushort* VTg = Kb + SZ;                          // [b][e][tok]
    ushort* WT  = VTg + SZ;                         // 60 x 64K bf16 transposed weights

    k_wprep<<<dim3(NLAYER * 5), dim3(256), 0, stream>>>(Wq, Wk, Wv, W1, W2, WT);
    k_embed<<<dim3(2048), dim3(256), 0, stream>>>(xs, ys, W_in, b_in, Hb);
    for (int i = 0; i < NLAYER; ++i) {
        const size_t vo = (size_t)i * E;
        const ushort* WqT = WT + ((size_t)(i * 5 + 0) << 16);
        const ushort* WkT = WT + ((size_t)(i * 5 + 1) << 16);
        const ushort* WvT = WT + ((size_t)(i * 5 + 2) << 16);
        const ushort* W1T = WT + ((size_t)(i * 5 + 3) << 16);
        const ushort* W2T = WT + ((size_t)(i * 5 + 4) << 16);
        k_qkv<<<dim3(512), dim3(256), 0, stream>>>(Hb, WqT, WkT, WvT, Qb, Kb, VTg);
        k_attn<<<dim3(256), dim3(512), 0, stream>>>(Qb, Kb, VTg, Hb, g1 + vo, be1 + vo);
        k_mlp<<<dim3(512), dim3(256), 0, stream>>>(Hb, W1T, b1 + vo, W2T, b2 + vo,
                                                   g2 + vo, be2 + vo);
    }
    k_readout<<<dim3((NB * NTOK) / 4), dim3(256), 0, stream>>>(Hb, W_out, b_out, (float*)d_out);
}

// Round 18
// 1483.567 us; speedup vs baseline: 1.7003x; 1.7003x over previous
//
#include <hip/hip_runtime.h>
#include <math.h>

#define E 256
#define NTOK 1024
#define NB 32
#define NLAYER 12
#define LN_EPS 1e-5f

typedef __attribute__((ext_vector_type(8))) short bf16x8;
typedef __attribute__((ext_vector_type(4))) float f32x4;
#define MFMA16(a, b, c) __builtin_amdgcn_mfma_f32_16x16x32_bf16(a, b, c, 0, 0, 0)

__device__ __forceinline__ ushort f2bf(float f) {
    union { float f; unsigned u; } v; v.f = f;
    return (ushort)((v.u + 0x7fffu + ((v.u >> 16) & 1u)) >> 16);
}
__device__ __forceinline__ float bf2f(ushort u) {
    union { unsigned u; float f; } v; v.u = (unsigned)u << 16;
    return v.f;
}

// ---------------------------------------------------------------- weight prep
__global__ __launch_bounds__(256) void k_wprep(
    const float* __restrict__ Wq, const float* __restrict__ Wk, const float* __restrict__ Wv,
    const float* __restrict__ W1, const float* __restrict__ W2,
    ushort* __restrict__ WT)
{
    const int mat = blockIdx.x % 5;
    const int l   = blockIdx.x / 5;
    const float* src = (mat == 0 ? Wq : mat == 1 ? Wk : mat == 2 ? Wv : mat == 3 ? W1 : W2)
                       + (size_t)l * E * E;
    ushort* dst = WT + ((size_t)(l * 5 + mat) << 16);
    const int n = threadIdx.x;
    #pragma unroll
    for (int c = 0; c < 4; ++c) {
        #pragma unroll
        for (int j = 0; j < 8; ++j) {
            const int k0 = c * 64 + j * 8;
            uint4 u;
            u.x = (uint)f2bf(src[(size_t)(k0 + 0) * E + n]) | ((uint)f2bf(src[(size_t)(k0 + 1) * E + n]) << 16);
            u.y = (uint)f2bf(src[(size_t)(k0 + 2) * E + n]) | ((uint)f2bf(src[(size_t)(k0 + 3) * E + n]) << 16);
            u.z = (uint)f2bf(src[(size_t)(k0 + 4) * E + n]) | ((uint)f2bf(src[(size_t)(k0 + 5) * E + n]) << 16);
            u.w = (uint)f2bf(src[(size_t)(k0 + 6) * E + n]) | ((uint)f2bf(src[(size_t)(k0 + 7) * E + n]) << 16);
            *(uint4*)&dst[(size_t)n * E + k0] = u;
        }
    }
}

// ---------------------------------------------------------------- embed (bf16 residual; XCD-affine)
__global__ __launch_bounds__(256) void k_embed(
    const float* __restrict__ xs, const float* __restrict__ ys,
    const float* __restrict__ W_in, const float* __restrict__ b_in,
    ushort* __restrict__ Hb)
{
    __shared__ float zs[16][64];
    const int tid = threadIdx.x;
    const int bid = blockIdx.x;
    const int r0 = (bid & 31) * NTOK + (bid >> 5) * 16;   // batch = bid&31 -> XCD b%8
    #pragma unroll
    for (int l = 0; l < 4; ++l) {
        int lin = tid + l * 256;
        int i = lin >> 6, d = lin & 63;
        int row = r0 + i;
        int t = row & (NTOK - 1);
        float v;
        if (d < 63) v = xs[(size_t)row * 63 + d];
        else        v = (t == NTOK - 1) ? 0.f : ys[row];
        zs[i][d] = v;
    }
    __syncthreads();
    float acc[16];
    #pragma unroll
    for (int i = 0; i < 16; ++i) acc[i] = 0.f;
    for (int d = 0; d < 64; ++d) {
        float w = W_in[d * E + tid];
        #pragma unroll
        for (int i = 0; i < 16; ++i) acc[i] = fmaf(zs[i][d], w, acc[i]);
    }
    float bb = b_in[tid];
    #pragma unroll
    for (int i = 0; i < 16; ++i)
        Hb[(size_t)(r0 + i) * E + tid] = f2bf(acc[i] + bb);
}

// ---------------------------------------------------------------- qkv helpers (ALL static indexing)
// GEMM with register-prefetched weight staging (race-free: registers private).
__device__ __forceinline__ void qkv_gemm(
    const ushort* __restrict__ Wt, const ushort* __restrict__ Hb,
    size_t r0, int tid, int w, int lr, int lg,
    ushort (&Ws)[256][72], f32x4 (&acc)[4][4])
{
    #pragma unroll
    for (int mt = 0; mt < 4; ++mt)
        #pragma unroll
        for (int nt = 0; nt < 4; ++nt) acc[mt][nt] = (f32x4){0.f, 0.f, 0.f, 0.f};

    const int sn = tid >> 3;
    const int ss = tid & 7;
    bf16x8 c[8];
    #pragma unroll
    for (int rep = 0; rep < 8; ++rep)
        c[rep] = *(const bf16x8*)&Wt[(size_t)(rep * 32 + sn) * E + ss * 8];

    #pragma unroll 1
    for (int kc = 0; kc < 4; ++kc) {
        __syncthreads();                          // prev compute done reading Ws
        #pragma unroll
        for (int rep = 0; rep < 8; ++rep)
            *(bf16x8*)&Ws[rep * 32 + sn][ss * 8] = c[rep];
        {                                         // prefetch next chunk (wraps; unused at kc=3)
            const int kn = ((kc + 1) & 3) * 64;
            #pragma unroll
            for (int rep = 0; rep < 8; ++rep)
                c[rep] = *(const bf16x8*)&Wt[(size_t)(rep * 32 + sn) * E + kn + ss * 8];
        }
        __syncthreads();
        #pragma unroll
        for (int kl = 0; kl < 2; ++kl) {
            bf16x8 af[4], bw[4];
            #pragma unroll
            for (int mt = 0; mt < 4; ++mt)
                af[mt] = *(const bf16x8*)&Hb[(r0 + mt * 16 + lr) * E + kc * 64 + kl * 32 + lg * 8];
            #pragma unroll
            for (int nt = 0; nt < 4; ++nt)
                bw[nt] = *(const bf16x8*)&Ws[w * 64 + nt * 16 + lr][kl * 32 + lg * 8];
            #pragma unroll
            for (int mt = 0; mt < 4; ++mt)
                #pragma unroll
                for (int nt = 0; nt < 4; ++nt)
                    acc[mt][nt] = MFMA16(af[mt], bw[nt], acc[mt][nt]);
        }
    }
}

__device__ __forceinline__ void qkv_out_qk(
    ushort* __restrict__ Out, size_t r0, int w, int l, int lr, int lg,
    ushort (&ScW)[16][72], f32x4 (&acc)[4][4])
{
    #pragma unroll
    for (int mt = 0; mt < 4; ++mt) {              // STATIC mt: acc stays in registers
        #pragma unroll
        for (int nt = 0; nt < 4; ++nt)
            #pragma unroll
            for (int r = 0; r < 4; ++r)
                ScW[lg * 4 + r][nt * 16 + lr] = f2bf(acc[mt][nt][r]);
        #pragma unroll
        for (int j = 0; j < 2; ++j) {             // same-wave RAW via LDS
            bf16x8 v = *(const bf16x8*)&ScW[l >> 2][(l & 3) * 16 + j * 8];
            *(bf16x8*)&Out[(r0 + mt * 16 + (l >> 2)) * E + w * 64 + (l & 3) * 16 + j * 8] = v;
        }
    }
}

// ---------------------------------------------------------------- MFMA qkv (register-blocked; XCD-affine)
__global__ __launch_bounds__(256, 2) void k_qkv(
    const ushort* __restrict__ Hb,
    const ushort* __restrict__ WqT, const ushort* __restrict__ WkT, const ushort* __restrict__ WvT,
    ushort* __restrict__ Qb, ushort* __restrict__ Kb, ushort* __restrict__ VTg)
{
    __shared__ __align__(16) ushort Ws[256][72];    // weights chunk; reused as V out-stage
    __shared__ __align__(16) ushort Sc[4][16][72];  // per-wave Q/K out-scratch
    const int tid = threadIdx.x;
    const int w = tid >> 6, l = tid & 63;
    const int lr = l & 15, lg = l >> 4;
    const int bid  = blockIdx.x;
    const int b    = bid & 31;                      // batch -> XCD b%8 (matches k_attn)
    const int tok0 = (bid >> 5) * 64;
    const size_t r0 = (size_t)b * NTOK + tok0;

    f32x4 acc[4][4];

    qkv_gemm(WqT, Hb, r0, tid, w, lr, lg, Ws, acc);
    qkv_out_qk(Qb, r0, w, l, lr, lg, Sc[w], acc);

    qkv_gemm(WkT, Hb, r0, tid, w, lr, lg, Ws, acc);
    qkv_out_qk(Kb, r0, w, l, lr, lg, Sc[w], acc);

    qkv_gemm(WvT, Hb, r0, tid, w, lr, lg, Ws, acc);
    // V epilogue: stage [e][tok] tile in Ws, then coalesced 128B copy-out
    __syncthreads();                              // all waves done reading weights
    #pragma unroll
    for (int mt = 0; mt < 4; ++mt)
        #pragma unroll
        for (int nt = 0; nt < 4; ++nt) {
            ushort4 u;
            u.x = f2bf(acc[mt][nt][0]); u.y = f2bf(acc[mt][nt][1]);
            u.z = f2bf(acc[mt][nt][2]); u.w = f2bf(acc[mt][nt][3]);
            *(ushort4*)&Ws[w * 64 + nt * 16 + lr][mt * 16 + lg * 4] = u;
        }
    __syncthreads();
    #pragma unroll
    for (int rep = 0; rep < 8; ++rep) {
        int lin = rep * 256 + tid;
        int row = lin >> 3, ch = lin & 7;         // 8 lanes = 128B contiguous per e-row
        bf16x8 v = *(const bf16x8*)&Ws[row][ch * 8];
        *(bf16x8*)&VTg[((size_t)b * E + row) * NTOK + tok0 + ch * 8] = v;
    }
}

// ---------------------------------------------------------------- MFMA attention + residual + LN1
// R16 config (best measured: 65.9us): 512 thr = 8 waves x 16 q-rows, grid 256.
// K and VT staged in LDS with register prefetch; residual rows prefetched.
#define ATTN_LOAD_TILE(koff, ka, kb_, va_, vb_)                                          \
    ka  = *(const bf16x8*)&Kb [kvbase + (size_t)((koff) + (tid >> 5)) * E + (tid & 31) * 8];       \
    kb_ = *(const bf16x8*)&Kb [kvbase + (size_t)((koff) + 16 + (tid >> 5)) * E + (tid & 31) * 8];  \
    va_ = *(const bf16x8*)&VTg[vtbase + (size_t)(tid >> 2) * NTOK + (koff) + (tid & 3) * 8];       \
    vb_ = *(const bf16x8*)&VTg[vtbase + (size_t)(128 + (tid >> 2)) * NTOK + (koff) + (tid & 3) * 8];

__global__ __launch_bounds__(512, 2) void k_attn(
    const ushort* __restrict__ Qb, const ushort* __restrict__ Kb, const ushort* __restrict__ VTg,
    ushort* __restrict__ Hb,
    const float* __restrict__ g1, const float* __restrict__ be1)
{
    __shared__ __align__(16) ushort Ks[32][264];
    __shared__ __align__(16) ushort VT[256][40];
    __shared__ __align__(16) ushort Pl[8][16][40];
    const int tid = threadIdx.x;
    const int w  = tid >> 6, l = tid & 63;
    const int lr = l & 15, lg = l >> 4;

    // bid mod 8 = batch mod 8 -> all 8 q-tiles of a batch on one XCD (4MB KV = L2)
    const int bid   = blockIdx.x;
    const int batch = bid & 31;
    const int tile  = bid >> 5;

    const size_t kvbase = (size_t)batch * NTOK * E;
    const size_t vtbase = (size_t)batch * E * NTOK;
    const int    qrow0  = tile * 128 + w * 16;
    const size_t qbase  = kvbase + (size_t)qrow0 * E;

    // Q fragments: 16 rows x 256, register-resident
    bf16x8 qf[8];
    #pragma unroll
    for (int kk = 0; kk < 8; ++kk)
        qf[kk] = *(const bf16x8*)&Qb[qbase + (size_t)lr * E + kk * 32 + lg * 8];

    // prefetch residual rows for the epilogue (latency hidden under K-loop)
    ushort hr[4][16];
    #pragma unroll
    for (int r = 0; r < 4; ++r)
        #pragma unroll
        for (int nt = 0; nt < 16; ++nt)
            hr[r][nt] = Hb[kvbase + (size_t)(qrow0 + lg * 4 + r) * E + nt * 16 + lr];

    f32x4 o[16];
    #pragma unroll
    for (int nt = 0; nt < 16; ++nt) o[nt] = (f32x4){0.f, 0.f, 0.f, 0.f};

    const float inv_n = 1.0f / (float)NTOK;
    // Pl column swizzle: XOR 8-chunk by bit3 of q-row
    const int wsw = ((lg >> 1) & 1) << 3;
    const int rsw = ((lr >> 3) & 1) << 3;

    // prologue: tile 0 -> registers
    bf16x8 cka, ckb, cva, cvb;
    ATTN_LOAD_TILE(0, cka, ckb, cva, cvb);

    #pragma unroll 1
    for (int jt = 0; jt < 32; ++jt) {
        __syncthreads();                          // prior compute's LDS reads done (WAR)
        *(bf16x8*)&Ks[ 0 + (tid >> 5)][(tid & 31) * 8] = cka;
        *(bf16x8*)&Ks[16 + (tid >> 5)][(tid & 31) * 8] = ckb;
        *(bf16x8*)&VT[  0 + (tid >> 2)][(tid & 3) * 8] = cva;
        *(bf16x8*)&VT[128 + (tid >> 2)][(tid & 3) * 8] = cvb;
        // issue next tile's global loads (registers only; latency hides under MFMA)
        bf16x8 nka, nkb, nva, nvb;
        {
            const int kn = ((jt + 1) & 31) * 32;  // wraps at jt=31 (result unused)
            ATTN_LOAD_TILE(kn, nka, nkb, nva, nvb);
        }
        __syncthreads();                          // staging visible to all waves

        // S = Q K^T (two 16-col tiles)
        f32x4 s0 = (f32x4){0.f, 0.f, 0.f, 0.f};
        f32x4 s1 = (f32x4){0.f, 0.f, 0.f, 0.f};
        #pragma unroll
        for (int kk = 0; kk < 8; ++kk) {
            bf16x8 b0 = *(const bf16x8*)&Ks[lr][kk * 32 + lg * 8];
            bf16x8 b1 = *(const bf16x8*)&Ks[16 + lr][kk * 32 + lg * 8];
            s0 = MFMA16(qf[kk], b0, s0);
            s1 = MFMA16(qf[kk], b1, s1);
        }
        // P = relu(S)/n -> Pl (col 8-chunk swizzled); same-wave write->read
        #pragma unroll
        for (int r = 0; r < 4; ++r) {
            Pl[w][lg * 4 + r][lr ^ wsw]        = f2bf(fmaxf(s0[r], 0.f) * inv_n);
            Pl[w][lg * 4 + r][(16 + lr) ^ wsw] = f2bf(fmaxf(s1[r], 0.f) * inv_n);
        }
        bf16x8 pa = *(const bf16x8*)&Pl[w][lr][(lg * 8) ^ rsw];
        // O += P V
        #pragma unroll
        for (int nt = 0; nt < 16; ++nt) {
            bf16x8 vb = *(const bf16x8*)&VT[nt * 16 + lr][lg * 8];
            o[nt] = MFMA16(pa, vb, o[nt]);
        }
        // rotate prefetch regs
        cka = nka; ckb = nkb; cva = nva; cvb = nvb;
    }

    // epilogue: residual (prefetched bf16 carrier) + LayerNorm (fp32 in-register)
    float gg[16], bb[16];
    #pragma unroll
    for (int nt = 0; nt < 16; ++nt) {
        gg[nt] = g1[nt * 16 + lr];
        bb[nt] = be1[nt * 16 + lr];
    }
    #pragma unroll
    for (int r = 0; r < 4; ++r) {
        const int q = lg * 4 + r;
        const size_t rowbase = kvbase + (size_t)(qrow0 + q) * E;
        float xv[16];
        float s = 0.f, s2 = 0.f;
        #pragma unroll
        for (int nt = 0; nt < 16; ++nt) {
            float val = bf2f(hr[r][nt]) + o[nt][r];
            xv[nt] = val;
            s += val; s2 += val * val;
        }
        #pragma unroll
        for (int m = 1; m < 16; m <<= 1) {
            s  += __shfl_xor(s, m, 64);
            s2 += __shfl_xor(s2, m, 64);
        }
        float mu = s * (1.f / 256.f);
        float rs = rsqrtf(s2 * (1.f / 256.f) - mu * mu + LN_EPS);
        #pragma unroll
        for (int nt = 0; nt < 16; ++nt) {
            float ov = (xv[nt] - mu) * rs * gg[nt] + bb[nt];
            Hb[rowbase + nt * 16 + lr] = f2bf(ov);
        }
    }
}

// ---------------------------------------------------------------- MFMA MLP (register-blocked; XCD-affine) + residual + LN2
__global__ __launch_bounds__(256, 2) void k_mlp(
    ushort* __restrict__ Hb,
    const ushort* __restrict__ W1T, const float* __restrict__ b1,
    const ushort* __restrict__ W2T, const float* __restrict__ b2,
    const float* __restrict__ g2, const float* __restrict__ be2)
{
    __shared__ __align__(16) ushort Ws[256][72];
    __shared__ __align__(16) ushort Ts[64][264];
    __shared__ float part[4][64][2];
    __shared__ float stats[64][2];
    const int tid = threadIdx.x;
    const int w = tid >> 6, l = tid & 63;
    const int lr = l & 15, lg = l >> 4;
    const int bid = blockIdx.x;
    const size_t r0 = (size_t)(bid & 31) * NTOK + (bid >> 5) * 64;  // XCD-affine
    const int sn = tid >> 3, ss = tid & 7;

    // ---- GEMM1: T = relu(H @ W1 + b1)   (reg-prefetched weight staging)
    f32x4 acc[4][4];
    qkv_gemm(W1T, Hb, r0, tid, w, lr, lg, Ws, acc);
    {
        float bb1[4];
        #pragma unroll
        for (int nt = 0; nt < 4; ++nt) bb1[nt] = b1[w * 64 + nt * 16 + lr];
        #pragma unroll
        for (int mt = 0; mt < 4; ++mt)
            #pragma unroll
            for (int nt = 0; nt < 4; ++nt)
                #pragma unroll
                for (int r = 0; r < 4; ++r)
                    Ts[mt * 16 + lg * 4 + r][w * 64 + nt * 16 + lr]
                        = f2bf(fmaxf(acc[mt][nt][r] + bb1[nt], 0.f));
    }

    // ---- GEMM2: out = T @ W2   (reg-prefetched weight staging)
    f32x4 acc2[4][4];
    #pragma unroll
    for (int mt = 0; mt < 4; ++mt)
        #pragma unroll
        for (int nt = 0; nt < 4; ++nt) acc2[mt][nt] = (f32x4){0.f, 0.f, 0.f, 0.f};
    bf16x8 c2[8];
    #pragma unroll
    for (int rep = 0; rep < 8; ++rep)
        c2[rep] = *(const bf16x8*)&W2T[(size_t)(rep * 32 + sn) * E + ss * 8];
    #pragma unroll 1
    for (int kc = 0; kc < 4; ++kc) {
        __syncthreads();                          // prev compute done; orders Ts writes->reads
        #pragma unroll
        for (int rep = 0; rep < 8; ++rep)
            *(bf16x8*)&Ws[rep * 32 + sn][ss * 8] = c2[rep];
        {
            const int kn = ((kc + 1) & 3) * 64;
            #pragma unroll
            for (int rep = 0; rep < 8; ++rep)
                c2[rep] = *(const bf16x8*)&W2T[(size_t)(rep * 32 + sn) * E + kn + ss * 8];
        }
        __syncthreads();
        #pragma unroll
        for (int kl = 0; kl < 2; ++kl) {
            bf16x8 af[4], bw[4];
            #pragma unroll
            for (int mt = 0; mt < 4; ++mt)
                af[mt] = *(const bf16x8*)&Ts[mt * 16 + lr][kc * 64 + kl * 32 + lg * 8];
            #pragma unroll
            for (int nt = 0; nt < 4; ++nt)
                bw[nt] = *(const bf16x8*)&Ws[w * 64 + nt * 16 + lr][kl * 32 + lg * 8];
            #pragma unroll
            for (int mt = 0; mt < 4; ++mt)
                #pragma unroll
                for (int nt = 0; nt < 4; ++nt)
                    acc2[mt][nt] = MFMA16(af[mt], bw[nt], acc2[mt][nt]);
        }
    }

    // ---- residual (bf16 carrier) + LN2 (cross-wave row reduction)
    {
        float b2v[4];
        #pragma unroll
        for (int nt = 0; nt < 4; ++nt) b2v[nt] = b2[w * 64 + nt * 16 + lr];
        #pragma unroll
        for (int mt = 0; mt < 4; ++mt)
            #pragma unroll
            for (int r = 0; r < 4; ++r)
                #pragma unroll
                for (int nt = 0; nt < 4; ++nt)
                    acc2[mt][nt][r] += bf2f(Hb[(r0 + mt * 16 + lg * 4 + r) * E + w * 64 + nt * 16 + lr])
                                       + b2v[nt];
    }
    #pragma unroll
    for (int mt = 0; mt < 4; ++mt)
        #pragma unroll
        for (int r = 0; r < 4; ++r) {
            float s = 0.f, s2 = 0.f;
            #pragma unroll
            for (int nt = 0; nt < 4; ++nt) {
                float v = acc2[mt][nt][r];
                s += v; s2 += v * v;
            }
            #pragma unroll
            for (int m = 1; m < 16; m <<= 1) {
                s  += __shfl_xor(s, m, 64);
                s2 += __shfl_xor(s2, m, 64);
            }
            if (lr == 0) {
                part[w][mt * 16 + lg * 4 + r][0] = s;
                part[w][mt * 16 + lg * 4 + r][1] = s2;
            }
        }
    __syncthreads();
    if (tid < 64) {
        float s = part[0][tid][0] + part[1][tid][0] + part[2][tid][0] + part[3][tid][0];
        float s2 = part[0][tid][1] + part[1][tid][1] + part[2][tid][1] + part[3][tid][1];
        float mu = s * (1.f / 256.f);
        stats[tid][0] = mu;
        stats[tid][1] = rsqrtf(s2 * (1.f / 256.f) - mu * mu + LN_EPS);
    }
    __syncthreads();
    {
        float gg[4], be[4];
        #pragma unroll
        for (int nt = 0; nt < 4; ++nt) {
            gg[nt] = g2[w * 64 + nt * 16 + lr];
            be[nt] = be2[w * 64 + nt * 16 + lr];
        }
        #pragma unroll
        for (int mt = 0; mt < 4; ++mt)
            #pragma unroll
            for (int r = 0; r < 4; ++r) {
                const int row = mt * 16 + lg * 4 + r;
                const float mu = stats[row][0], rs = stats[row][1];
                const size_t rowbase = (r0 + row) * E;
                #pragma unroll
                for (int nt = 0; nt < 4; ++nt) {
                    float ov = (acc2[mt][nt][r] - mu) * rs * gg[nt] + be[nt];
                    Hb[rowbase + w * 64 + nt * 16 + lr] = f2bf(ov);
                }
            }
    }
}

// ---------------------------------------------------------------- readout
__global__ __launch_bounds__(256) void k_readout(
    const ushort* __restrict__ Hb, const float* __restrict__ W_out,
    const float* __restrict__ b_out, float* __restrict__ out)
{
    const int tid = threadIdx.x;
    const int lane = tid & 63;
    const int row = blockIdx.x * 4 + (tid >> 6);
    float s = 0.f;
    #pragma unroll
    for (int j = 0; j < 4; ++j)
        s += bf2f(Hb[(size_t)row * E + j * 64 + lane]) * W_out[j * 64 + lane];
    #pragma unroll
    for (int m = 1; m < 64; m <<= 1) s += __shfl_xor(s, m, 64);
    if (lane == 0) out[row] = s + b_out[0];
}

// ----------------------------------------------------------------
extern "C" void kernel_launch(void* const* d_in, const int* in_sizes, int n_in,
                              void* d_out, int out_size, void* d_ws, size_t ws_size,
                              hipStream_t stream)
{
    const float* xs    = (const float*)d_in[0];
    const float* ys    = (const float*)d_in[1];
    const float* W_in  = (const float*)d_in[2];
    const float* b_in  = (const float*)d_in[3];
    const float* Wq    = (const float*)d_in[4];
    const float* Wk    = (const float*)d_in[5];
    const float* Wv    = (const float*)d_in[6];
    const float* g1    = (const float*)d_in[7];
    const float* be1   = (const float*)d_in[8];
    const float* W1    = (const float*)d_in[9];
    const float* b1    = (const float*)d_in[10];
    const float* W2    = (const float*)d_in[11];
    const float* b2    = (const float*)d_in[12];
    const float* g2    = (const float*)d_in[13];
    const float* be2   = (const float*)d_in[14];
    const float* W_out = (const float*)d_in[15];
    const float* b_out = (const float*)d_in[16];
    (void)in_sizes; (void)n_in; (void)out_size; (void)ws_size;

    const size_t SZ = (size_t)NB * NTOK * E;
    ushort* Hb  = (ushort*)d_ws;                    // bf16 residual stream
    ushort* Qb  = Hb + SZ;
    ushort* Kb  = Qb + SZ;
    ushort* VTg = Kb + SZ;                          // [b][e][tok]
    ushort* WT  = VTg + SZ;                         // 60 x 64K bf16 transposed weights

    k_wprep<<<dim3(NLAYER * 5), dim3(256), 0, stream>>>(Wq, Wk, Wv, W1, W2, WT);
    k_embed<<<dim3(2048), dim3(256), 0, stream>>>(xs, ys, W_in, b_in, Hb);
    for (int i = 0; i < NLAYER; ++i) {
        const size_t vo = (size_t)i * E;
        const ushort* WqT = WT + ((size_t)(i * 5 + 0) << 16);
        const ushort* WkT = WT + ((size_t)(i * 5 + 1) << 16);
        const ushort* WvT = WT + ((size_t)(i * 5 + 2) << 16);
        const ushort* W1T = WT + ((size_t)(i * 5 + 3) << 16);
        const ushort* W2T = WT + ((size_t)(i * 5 + 4) << 16);
        k_qkv<<<dim3(512), dim3(256), 0, stream>>>(Hb, WqT, WkT, WvT, Qb, Kb, VTg);
        k_attn<<<dim3(256), dim3(512), 0, stream>>>(Qb, Kb, VTg, Hb, g1 + vo, be1 + vo);
        k_mlp<<<dim3(512), dim3(256), 0, stream>>>(Hb, W1T, b1 + vo, W2T, b2 + vo,
                                                   g2 + vo, be2 + vo);
    }
    k_readout<<<dim3((NB * NTOK) / 4), dim3(256), 0, stream>>>(Hb, W_out, b_out, (float*)d_out);
}